// Round 1
// baseline (1334.898 us; speedup 1.0000x reference)
//
#include <hip/hip_runtime.h>
#include <cmath>
#include <climits>

#define NB 32
#define HH 512
#define WW 512
#define NC 21
#define PIX (HH * WW)              // 262144 pixels per sample
#define BLOCK 256
#define BLOCKS_PER_SAMPLE (PIX / BLOCK)  // 1024

// ws layout: int ws[NB][8] = {pymin, pxmin, pymax, pxmax, tymin, txmin, tymax, txmax}
// mins init to INT_MAX, maxes to -1. has_* derived as (ymax >= 0).

__global__ void init_ws_kernel(int* __restrict__ ws) {
    int i = threadIdx.x;
    if (i < NB * 8) {
        int f = i & 7;
        ws[i] = ((f & 2) == 0) ? INT_MAX : -1;  // f=0,1,4,5 are mins; 2,3,6,7 are maxes
    }
}

__global__ __launch_bounds__(BLOCK) void bbox_reduce_kernel(
    const float* __restrict__ pred, const float* __restrict__ tru,
    int* __restrict__ ws) {
    int bid = blockIdx.x;
    int b = bid >> 10;                      // / BLOCKS_PER_SAMPLE
    int p = ((bid & 1023) << 8) + threadIdx.x;  // pixel index within sample
    int y = p >> 9;                          // / WW
    int x = p & 511;                         // % WW
    size_t off = ((size_t)b * PIX + (size_t)p) * NC;

    // mask = argmax(channel) > 0  <=>  max(p[1..20]) > p[0]  (ties -> index 0)
    float p0 = pred[off];
    float pmx = pred[off + 1];
#pragma unroll
    for (int c = 2; c < NC; ++c) pmx = fmaxf(pmx, pred[off + c]);
    bool pm = pmx > p0;

    float t0 = tru[off];
    float tmx = tru[off + 1];
#pragma unroll
    for (int c = 2; c < NC; ++c) tmx = fmaxf(tmx, tru[off + c]);
    bool tm = tmx > t0;

    int v0 = pm ? y : INT_MAX;
    int v1 = pm ? x : INT_MAX;
    int v2 = pm ? y : -1;
    int v3 = pm ? x : -1;
    int v4 = tm ? y : INT_MAX;
    int v5 = tm ? x : INT_MAX;
    int v6 = tm ? y : -1;
    int v7 = tm ? x : -1;

    // wave64 butterfly reduction
#pragma unroll
    for (int s = 32; s >= 1; s >>= 1) {
        v0 = min(v0, __shfl_xor(v0, s));
        v1 = min(v1, __shfl_xor(v1, s));
        v2 = max(v2, __shfl_xor(v2, s));
        v3 = max(v3, __shfl_xor(v3, s));
        v4 = min(v4, __shfl_xor(v4, s));
        v5 = min(v5, __shfl_xor(v5, s));
        v6 = max(v6, __shfl_xor(v6, s));
        v7 = max(v7, __shfl_xor(v7, s));
    }

    __shared__ int sm[8];
    if (threadIdx.x < 8) sm[threadIdx.x] = ((threadIdx.x & 2) == 0) ? INT_MAX : -1;
    __syncthreads();
    if ((threadIdx.x & 63) == 0) {  // one leader per wave (4 waves)
        atomicMin(&sm[0], v0);
        atomicMin(&sm[1], v1);
        atomicMax(&sm[2], v2);
        atomicMax(&sm[3], v3);
        atomicMin(&sm[4], v4);
        atomicMin(&sm[5], v5);
        atomicMax(&sm[6], v6);
        atomicMax(&sm[7], v7);
    }
    __syncthreads();
    if (threadIdx.x < 8) {
        int f = threadIdx.x;
        int val = sm[f];
        int* dst = &ws[b * 8 + f];
        if ((f & 2) == 0) {
            if (val != INT_MAX) atomicMin(dst, val);
        } else {
            if (val >= 0) atomicMax(dst, val);
        }
    }
}

__global__ void finalize_kernel(const int* __restrict__ ws, float* __restrict__ out) {
    int b = threadIdx.x;  // 64 threads; lanes 32..63 contribute 0
    float pen = 0.0f;
    if (b < NB) {
        const int* w = ws + b * 8;
        bool has_p = w[2] >= 0;
        bool has_t = w[6] >= 0;
        float p0, p1, p2, p3, t0, t1, t2, t3;
        if (has_p) { p0 = (float)w[0]; p1 = (float)w[1]; p2 = (float)w[2]; p3 = (float)w[3]; }
        else       { p0 = 0.f; p1 = 0.f; p2 = 1.f; p3 = 1.f; }
        if (has_t) { t0 = (float)w[4]; t1 = (float)w[5]; t2 = (float)w[6]; t3 = (float)w[7]; }
        else       { t0 = 0.f; t1 = 0.f; t2 = 1.f; t3 = 1.f; }

        float pred_area = (p2 - p0 + 1.f) * (p3 - p1 + 1.f);
        float true_area = (t2 - t0 + 1.f) * (t3 - t1 + 1.f);
        float area_pen = fmaxf(pred_area - true_area, 0.f) / (true_area + 1.f);

        float cy = (p0 + p2) * 0.5f - (t0 + t2) * 0.5f;
        float cx = (p1 + p3) * 0.5f - (t1 + t3) * 0.5f;
        float center = sqrtf(cy * cy + cx * cx) * (1.0f / 20.0f);

        float iy = fminf(p2, t2) - fmaxf(p0, t0) + 1.f;
        float ix = fminf(p3, t3) - fmaxf(p1, t1) + 1.f;
        float inter = fmaxf(0.f, iy) * fmaxf(0.f, ix);
        float uni = pred_area + true_area - inter + 1e-6f;
        float iou_pen = 1.f - inter / uni;

        float total = area_pen + center + iou_pen;
        pen = (has_p && has_t) ? tanhf(total) : 0.f;
    }
#pragma unroll
    for (int s = 32; s >= 1; s >>= 1) pen += __shfl_xor(pen, s);
    if (threadIdx.x == 0) out[0] = 0.05f * (pen * (1.0f / NB));
}

extern "C" void kernel_launch(void* const* d_in, const int* in_sizes, int n_in,
                              void* d_out, int out_size, void* d_ws, size_t ws_size,
                              hipStream_t stream) {
    const float* pred = (const float*)d_in[0];
    const float* tru = (const float*)d_in[1];
    int* ws = (int*)d_ws;
    float* out = (float*)d_out;

    init_ws_kernel<<<1, 256, 0, stream>>>(ws);
    bbox_reduce_kernel<<<NB * BLOCKS_PER_SAMPLE, BLOCK, 0, stream>>>(pred, tru, ws);
    finalize_kernel<<<1, 64, 0, stream>>>(ws, out);
}